// Round 17
// baseline (51.247 us; speedup 1.0000x reference)
//
#include <hip/hip_runtime.h>

#define H 384
#define W 384
#define C 19
#define NB 4
#define HP 382               // H - K + 1
#define HW (H * W)
#define CHW (C * HW)
#define TOTAL_TERMS 47279376.0f   // NB * 81 * HP*HP

#define NBLOCKS 1152         // 147456 groups / 128

// number of kernel-offsets a in [0,2] with 0 <= a+d <= 2 and 0 <= p-a <= HP-1
__device__ __forceinline__ int multv(int p, int d) {
    int lo = max(max(0, -d), p - (HP - 1));
    int hi = min(min(2, 2 - d), p);
    return max(0, hi - lo + 1);
}

__device__ __forceinline__ float bce_fast(float x, float y) {
    // max(x,0) - x*y + log1p(exp(-|x|)), fast-math variant
    float t = __expf(-fabsf(x));
    return fmaxf(x, 0.0f) - x * y + __logf(1.0f + t);
}

// R12 skeleton (depth-2, 3-slot register pipeline, full-width mapping, XCD
// chunking, two-kernel tail — 28.4 µs proven) + shuffle-halo: the halo f2s
// come from neighbor lanes' main float4 via __shfl (DS pipe) instead of
// redundant L1 loads. Loads drop 9 -> 4 f4 per group-channel (L1 bytes
// 2.25x down — the measured wall). Mid-wave row-wrap halos are garbage but
// provably weight-0 (multv==0 off-image). Wave-edge lanes 0/63 take
// predicated f2 loads at clamped addresses.
__global__ __launch_bounds__(256) void affinity_partial(
        const float* __restrict__ logits,
        const int* __restrict__ labels,
        float* __restrict__ partial) {
    const int t    = threadIdx.x;
    const int lane = t & 63;
    const int wid  = t >> 6;
    const int par  = wid & 1;

    const int b   = blockIdx.x;
    const int blk = (b & 7) * (NBLOCKS / 8) + (b >> 3);   // XCD chunking
    const int g   = blk * 128 + (wid >> 1) * 64 + lane;
    const int px0 = (g % 96) * 4;
    const int rs  = g / 96;
    const int py  = rs % H;
    const int n   = rs / H;

    const int x0c   = max(0, px0 - 4);
    const int d1    = px0 - x0c;                   // 0 or 4 (main f4 -> cols px0..px0+3)
    const int d2    = min(W - 4, px0 + 4) - x0c;   // epilogue la only
    const int off_l = max(px0 - 2, 0) - x0c;       // f2: cols px0-2,-1 (clamped)
    const int off_r = min(px0 + 4, W - 2) - x0c;   // f2: cols px0+4,+5 (clamped)
    const int ro1   = (min(py + 1, H - 1) - py) * W;
    const int ro2   = (min(py + 2, H - 1) - py) * W;

    const float* p0  = logits + (size_t)n * CHW + (size_t)py * W + x0c;
    const int*   lb0 = labels + (size_t)n * HW + (size_t)py * W + x0c;
    const bool ln0  = (lane == 0);
    const bool ln63 = (lane == 63);

    float total = 0.0f;

    if (par == 0) {
        float acc[32];
#pragma unroll
        for (int k = 0; k < 32; ++k) acc[k] = 0.0f;

        float4 sM0[3], sM2[3];        // main f4, rows y and y+2
        float2 sRY[3], sR2[3], sL2[3]; // predicated wave-edge halos

#define P0L(ch, sl) {                                                     \
        const float* pr = p0 + (size_t)(ch) * HW;                         \
        sM0[sl] = *(const float4*)(pr + d1);                              \
        sM2[sl] = *(const float4*)(pr + ro2 + d1);                        \
        if (ln63) { sRY[sl] = *(const float2*)(pr + off_r);               \
                    sR2[sl] = *(const float2*)(pr + ro2 + off_r); }       \
        if (ln0)  { sL2[sl] = *(const float2*)(pr + ro2 + off_l); } }

#define P0C(sl) {                                                         \
        float ryx = __shfl_down(sM0[sl].x, 1, 64);                        \
        float ryy = __shfl_down(sM0[sl].y, 1, 64);                        \
        float r2x = __shfl_down(sM2[sl].x, 1, 64);                        \
        float r2y = __shfl_down(sM2[sl].y, 1, 64);                        \
        float l2x = __shfl_up(sM2[sl].z, 1, 64);                          \
        float l2y = __shfl_up(sM2[sl].w, 1, 64);                          \
        if (ln63) { ryx = sRY[sl].x; ryy = sRY[sl].y;                     \
                    r2x = sR2[sl].x; r2y = sR2[sl].y; }                   \
        if (ln0)  { l2x = sL2[sl].x; l2y = sL2[sl].y; }                   \
        const float a6[6] = {sM0[sl].x, sM0[sl].y, sM0[sl].z, sM0[sl].w,  \
                             ryx, ryy};                                   \
        const float e8[8] = {l2x, l2y,                                    \
                             sM2[sl].x, sM2[sl].y, sM2[sl].z, sM2[sl].w,  \
                             r2x, r2y};                                   \
        _Pragma("unroll")                                                 \
        for (int i = 0; i < 4; ++i) {                                     \
            const float s = a6[i];                                        \
            acc[i * 8 + 0] += s * s;                                      \
            acc[i * 8 + 1] += s * a6[i + 1];                              \
            acc[i * 8 + 2] += s * a6[i + 2];                              \
            _Pragma("unroll")                                             \
            for (int dxi = 0; dxi < 5; ++dxi)                             \
                acc[i * 8 + 3 + dxi] += s * e8[i + dxi];                  \
        } }

        P0L(0, 0) P0L(1, 1)
#pragma unroll
        for (int st = 0; st < 19; ++st) {
            if (st + 2 < 19) { P0L(st + 2, (st + 2) % 3) }
            P0C(st % 3)
        }

        int la[8], ler[12];
        *(int4*)&la[0]  = *(const int4*)(lb0 + d1);   // cols px0..px0+3
        *(int4*)&la[4]  = *(const int4*)(lb0 + d2);   // cols px0+4..px0+7
        *(int4*)&ler[0] = *(const int4*)(lb0 + ro2);
        *(int4*)&ler[4] = *(const int4*)(lb0 + ro2 + d1);
        *(int4*)&ler[8] = *(const int4*)(lb0 + ro2 + d2);

        const int wy0 = multv(py, 0);
        const int wy2 = multv(py, 2);
#pragma unroll
        for (int i = 0; i < 4; ++i) {
            const int px = px0 + i;
            int wx[5];
#pragma unroll
            for (int dxi = 0; dxi < 5; ++dxi) wx[dxi] = multv(px, dxi - 2);
            const int ls = la[i];
            total += (float)(wy0 * wx[2]) * bce_fast(acc[i * 8 + 0], 1.0f);
            total += 2.0f * (float)(wy0 * wx[3]) *
                     bce_fast(acc[i * 8 + 1], (ls == la[i + 1]) ? 1.0f : 0.0f);
            total += 2.0f * (float)(wy0 * wx[4]) *
                     bce_fast(acc[i * 8 + 2], (ls == la[i + 2]) ? 1.0f : 0.0f);
#pragma unroll
            for (int dxi = 0; dxi < 5; ++dxi)
                total += 2.0f * (float)(wy2 * wx[dxi]) *
                         bce_fast(acc[i * 8 + 3 + dxi],
                                  (ls == ler[2 + i + dxi]) ? 1.0f : 0.0f);
        }
    } else {
        float acc[20];
#pragma unroll
        for (int k = 0; k < 20; ++k) acc[k] = 0.0f;

        float4 sS[3], sM1[3];
        float2 sR1[3], sL1[3];

#define P1L(ch, sl) {                                                     \
        const float* pr = p0 + (size_t)(ch) * HW;                         \
        sS[sl]  = *(const float4*)(pr + d1);                              \
        sM1[sl] = *(const float4*)(pr + ro1 + d1);                        \
        if (ln63) { sR1[sl] = *(const float2*)(pr + ro1 + off_r); }       \
        if (ln0)  { sL1[sl] = *(const float2*)(pr + ro1 + off_l); } }

#define P1C(sl) {                                                         \
        float r1x = __shfl_down(sM1[sl].x, 1, 64);                        \
        float r1y = __shfl_down(sM1[sl].y, 1, 64);                        \
        float l1x = __shfl_up(sM1[sl].z, 1, 64);                          \
        float l1y = __shfl_up(sM1[sl].w, 1, 64);                          \
        if (ln63) { r1x = sR1[sl].x; r1y = sR1[sl].y; }                   \
        if (ln0)  { l1x = sL1[sl].x; l1y = sL1[sl].y; }                   \
        const float b8[8] = {l1x, l1y,                                    \
                             sM1[sl].x, sM1[sl].y, sM1[sl].z, sM1[sl].w,  \
                             r1x, r1y};                                   \
        const float s4[4] = {sS[sl].x, sS[sl].y, sS[sl].z, sS[sl].w};     \
        _Pragma("unroll")                                                 \
        for (int i = 0; i < 4; ++i) {                                     \
            const float s = s4[i];                                        \
            _Pragma("unroll")                                             \
            for (int dxi = 0; dxi < 5; ++dxi)                             \
                acc[i * 5 + dxi] += s * b8[i + dxi];                      \
        } }

        P1L(0, 0) P1L(1, 1)
#pragma unroll
        for (int st = 0; st < 19; ++st) {
            if (st + 2 < 19) { P1L(st + 2, (st + 2) % 3) }
            P1C(st % 3)
        }

        int la4[4], lbr[12];
        *(int4*)&la4[0] = *(const int4*)(lb0 + d1);
        *(int4*)&lbr[0] = *(const int4*)(lb0 + ro1);
        *(int4*)&lbr[4] = *(const int4*)(lb0 + ro1 + d1);
        *(int4*)&lbr[8] = *(const int4*)(lb0 + ro1 + d2);

        const int wy1 = multv(py, 1);
#pragma unroll
        for (int i = 0; i < 4; ++i) {
            const int px = px0 + i;
            int wx[5];
#pragma unroll
            for (int dxi = 0; dxi < 5; ++dxi) wx[dxi] = multv(px, dxi - 2);
            const int ls = la4[i];
#pragma unroll
            for (int dxi = 0; dxi < 5; ++dxi)
                total += 2.0f * (float)(wy1 * wx[dxi]) *
                         bce_fast(acc[i * 5 + dxi],
                                  (ls == lbr[2 + i + dxi]) ? 1.0f : 0.0f);
        }
    }

    // block reduction: wave shuffle then LDS across the 4 waves
#pragma unroll
    for (int off = 32; off > 0; off >>= 1) total += __shfl_down(total, off, 64);
    __shared__ float sm[4];
    if (lane == 0) sm[wid] = total;
    __syncthreads();
    if (t == 0)
        partial[blockIdx.x] = sm[0] + sm[1] + sm[2] + sm[3];
}

__global__ __launch_bounds__(256) void reduce_final(
        const float* __restrict__ partial, int n, float* __restrict__ out) {
    float s = 0.0f;
    for (int i = threadIdx.x; i < n; i += 256) s += partial[i];
#pragma unroll
    for (int off = 32; off > 0; off >>= 1) s += __shfl_down(s, off, 64);
    __shared__ float sm[4];
    const int lane = threadIdx.x & 63, wid = threadIdx.x >> 6;
    if (lane == 0) sm[wid] = s;
    __syncthreads();
    if (threadIdx.x == 0)
        out[0] = (sm[0] + sm[1] + sm[2] + sm[3]) / TOTAL_TERMS;
}

extern "C" void kernel_launch(void* const* d_in, const int* in_sizes, int n_in,
                              void* d_out, int out_size, void* d_ws, size_t ws_size,
                              hipStream_t stream) {
    const float* logits = (const float*)d_in[0];
    const int*   labels = (const int*)d_in[1];
    float* out     = (float*)d_out;
    float* partial = (float*)d_ws;   // 1152 floats

    affinity_partial<<<NBLOCKS, 256, 0, stream>>>(logits, labels, partial);
    reduce_final<<<1, 256, 0, stream>>>(partial, NBLOCKS, out);
}

// Round 18
// 28.364 us; speedup vs baseline: 1.8067x; 1.8067x over previous
//
#include <hip/hip_runtime.h>

#define H 384
#define W 384
#define C 19
#define NB 4
#define HP 382               // H - K + 1
#define HW (H * W)
#define CHW (C * HW)
#define TOTAL_TERMS 47279376.0f   // NB * 81 * HP*HP

#define NBLOCKS 1152         // 147456 groups / 128

// number of kernel-offsets a in [0,2] with 0 <= a+d <= 2 and 0 <= p-a <= HP-1
__device__ __forceinline__ int multv(int p, int d) {
    int lo = max(max(0, -d), p - (HP - 1));
    int hi = min(min(2, 2 - d), p);
    return max(0, hi - lo + 1);
}

__device__ __forceinline__ float bce_fast(float x, float y) {
    // max(x,0) - x*y + log1p(exp(-|x|)), fast-math variant
    float t = __expf(-fabsf(x));
    return fmaxf(x, 0.0f) - x * y + __logf(1.0f + t);
}

// FINAL: R12 configuration verbatim — the measured optimum (28.4 µs).
// Depth-2, 3-slot f4-only register software pipeline on the channel loop;
// 2-parity offset split per wave pair; full-width row-major group mapping;
// XCD-chunk swizzle; two-kernel tail.
// Proven-poison variants (do NOT reintroduce): f2-trimmed/mixed-width loads
// (VGPR 132), shuffle-halo (VGPR 204), depth-3 (VGPR 132), 128x4 tile remap
// (L2-stream break), LDS staging (barrier cadence), MFMA (band waste),
// single-kernel atomic tail with memset node (fill dispatch cost).
__global__ __launch_bounds__(256) void affinity_partial(
        const float* __restrict__ logits,
        const int* __restrict__ labels,
        float* __restrict__ partial) {
    const int t    = threadIdx.x;
    const int lane = t & 63;
    const int wid  = t >> 6;
    const int par  = wid & 1;

    const int b   = blockIdx.x;
    const int blk = (b & 7) * (NBLOCKS / 8) + (b >> 3);   // XCD chunking
    const int g   = blk * 128 + (wid >> 1) * 64 + lane;
    const int px0 = (g % 96) * 4;
    const int rs  = g / 96;
    const int py  = rs % H;
    const int n   = rs / H;

    // f4 at +d1 -> cols px0..px0+3, +d2 -> px0+4..+7, +0 -> px0-4..-1.
    // Degenerate edge slots only feed weight-0 terms (multv==0 off-image).
    const int x0c = max(0, px0 - 4);
    const int d1  = px0 - x0c;                 // 0 or 4
    const int d2  = min(W - 4, px0 + 4) - x0c; // 4 or 8 (==d1 at right edge)
    const int ro1 = (min(py + 1, H - 1) - py) * W;
    const int ro2 = (min(py + 2, H - 1) - py) * W;

    const float* p0  = logits + (size_t)n * CHW + (size_t)py * W + x0c;
    const int*   lb0 = labels + (size_t)n * HW + (size_t)py * W + x0c;

    float total = 0.0f;

    if (par == 0) {
        float acc[32];
#pragma unroll
        for (int k = 0; k < 32; ++k) acc[k] = 0.0f;

        float4 sA1[3], sA2[3], sE0[3], sE1[3], sE2[3];

#define P0L(ch, sl) {                                                     \
        const float* pr = p0 + (size_t)(ch) * HW;                         \
        sA1[sl] = *(const float4*)(pr + d1);                              \
        sA2[sl] = *(const float4*)(pr + d2);                              \
        sE0[sl] = *(const float4*)(pr + ro2);                             \
        sE1[sl] = *(const float4*)(pr + ro2 + d1);                        \
        sE2[sl] = *(const float4*)(pr + ro2 + d2); }

#define P0C(sl) {                                                         \
        const float a6[6] = {sA1[sl].x, sA1[sl].y, sA1[sl].z, sA1[sl].w,  \
                             sA2[sl].x, sA2[sl].y};                       \
        const float e8[8] = {sE0[sl].z, sE0[sl].w,                        \
                             sE1[sl].x, sE1[sl].y, sE1[sl].z, sE1[sl].w,  \
                             sE2[sl].x, sE2[sl].y};                       \
        _Pragma("unroll")                                                 \
        for (int i = 0; i < 4; ++i) {                                     \
            const float s = a6[i];                                        \
            acc[i * 8 + 0] += s * s;                                      \
            acc[i * 8 + 1] += s * a6[i + 1];                              \
            acc[i * 8 + 2] += s * a6[i + 2];                              \
            _Pragma("unroll")                                             \
            for (int dxi = 0; dxi < 5; ++dxi)                             \
                acc[i * 8 + 3 + dxi] += s * e8[i + dxi];                  \
        } }

        P0L(0, 0) P0L(1, 1)
#pragma unroll
        for (int st = 0; st < 19; ++st) {
            if (st + 2 < 19) { P0L(st + 2, (st + 2) % 3) }
            P0C(st % 3)
        }

        int la[8], ler[12];
        *(int4*)&la[0]  = *(const int4*)(lb0 + d1);   // cols px0..px0+3
        *(int4*)&la[4]  = *(const int4*)(lb0 + d2);   // cols px0+4..px0+7
        *(int4*)&ler[0] = *(const int4*)(lb0 + ro2);
        *(int4*)&ler[4] = *(const int4*)(lb0 + ro2 + d1);
        *(int4*)&ler[8] = *(const int4*)(lb0 + ro2 + d2);

        const int wy0 = multv(py, 0);
        const int wy2 = multv(py, 2);
#pragma unroll
        for (int i = 0; i < 4; ++i) {
            const int px = px0 + i;
            int wx[5];
#pragma unroll
            for (int dxi = 0; dxi < 5; ++dxi) wx[dxi] = multv(px, dxi - 2);
            const int ls = la[i];
            total += (float)(wy0 * wx[2]) * bce_fast(acc[i * 8 + 0], 1.0f);
            total += 2.0f * (float)(wy0 * wx[3]) *
                     bce_fast(acc[i * 8 + 1], (ls == la[i + 1]) ? 1.0f : 0.0f);
            total += 2.0f * (float)(wy0 * wx[4]) *
                     bce_fast(acc[i * 8 + 2], (ls == la[i + 2]) ? 1.0f : 0.0f);
#pragma unroll
            for (int dxi = 0; dxi < 5; ++dxi)
                total += 2.0f * (float)(wy2 * wx[dxi]) *
                         bce_fast(acc[i * 8 + 3 + dxi],
                                  (ls == ler[2 + i + dxi]) ? 1.0f : 0.0f);
        }
    } else {
        float acc[20];
#pragma unroll
        for (int k = 0; k < 20; ++k) acc[k] = 0.0f;

        float4 sS[3], sB0[3], sB1[3], sB2[3];

#define P1L(ch, sl) {                                                     \
        const float* pr = p0 + (size_t)(ch) * HW;                         \
        sS[sl]  = *(const float4*)(pr + d1);                              \
        sB0[sl] = *(const float4*)(pr + ro1);                             \
        sB1[sl] = *(const float4*)(pr + ro1 + d1);                        \
        sB2[sl] = *(const float4*)(pr + ro1 + d2); }

#define P1C(sl) {                                                         \
        const float b8[8] = {sB0[sl].z, sB0[sl].w,                        \
                             sB1[sl].x, sB1[sl].y, sB1[sl].z, sB1[sl].w,  \
                             sB2[sl].x, sB2[sl].y};                       \
        const float s4[4] = {sS[sl].x, sS[sl].y, sS[sl].z, sS[sl].w};     \
        _Pragma("unroll")                                                 \
        for (int i = 0; i < 4; ++i) {                                     \
            const float s = s4[i];                                        \
            _Pragma("unroll")                                             \
            for (int dxi = 0; dxi < 5; ++dxi)                             \
                acc[i * 5 + dxi] += s * b8[i + dxi];                      \
        } }

        P1L(0, 0) P1L(1, 1)
#pragma unroll
        for (int st = 0; st < 19; ++st) {
            if (st + 2 < 19) { P1L(st + 2, (st + 2) % 3) }
            P1C(st % 3)
        }

        int la4[4], lbr[12];
        *(int4*)&la4[0] = *(const int4*)(lb0 + d1);
        *(int4*)&lbr[0] = *(const int4*)(lb0 + ro1);
        *(int4*)&lbr[4] = *(const int4*)(lb0 + ro1 + d1);
        *(int4*)&lbr[8] = *(const int4*)(lb0 + ro1 + d2);

        const int wy1 = multv(py, 1);
#pragma unroll
        for (int i = 0; i < 4; ++i) {
            const int px = px0 + i;
            int wx[5];
#pragma unroll
            for (int dxi = 0; dxi < 5; ++dxi) wx[dxi] = multv(px, dxi - 2);
            const int ls = la4[i];
#pragma unroll
            for (int dxi = 0; dxi < 5; ++dxi)
                total += 2.0f * (float)(wy1 * wx[dxi]) *
                         bce_fast(acc[i * 5 + dxi],
                                  (ls == lbr[2 + i + dxi]) ? 1.0f : 0.0f);
        }
    }

    // block reduction: wave shuffle then LDS across the 4 waves
#pragma unroll
    for (int off = 32; off > 0; off >>= 1) total += __shfl_down(total, off, 64);
    __shared__ float sm[4];
    if (lane == 0) sm[wid] = total;
    __syncthreads();
    if (t == 0)
        partial[blockIdx.x] = sm[0] + sm[1] + sm[2] + sm[3];
}

__global__ __launch_bounds__(256) void reduce_final(
        const float* __restrict__ partial, int n, float* __restrict__ out) {
    float s = 0.0f;
    for (int i = threadIdx.x; i < n; i += 256) s += partial[i];
#pragma unroll
    for (int off = 32; off > 0; off >>= 1) s += __shfl_down(s, off, 64);
    __shared__ float sm[4];
    const int lane = threadIdx.x & 63, wid = threadIdx.x >> 6;
    if (lane == 0) sm[wid] = s;
    __syncthreads();
    if (threadIdx.x == 0)
        out[0] = (sm[0] + sm[1] + sm[2] + sm[3]) / TOTAL_TERMS;
}

extern "C" void kernel_launch(void* const* d_in, const int* in_sizes, int n_in,
                              void* d_out, int out_size, void* d_ws, size_t ws_size,
                              hipStream_t stream) {
    const float* logits = (const float*)d_in[0];
    const int*   labels = (const int*)d_in[1];
    float* out     = (float*)d_out;
    float* partial = (float*)d_ws;   // 1152 floats

    affinity_partial<<<NBLOCKS, 256, 0, stream>>>(logits, labels, partial);
    reduce_final<<<1, 256, 0, stream>>>(partial, NBLOCKS, out);
}